// Round 3
// baseline (2232.622 us; speedup 1.0000x reference)
//
#include <hip/hip_runtime.h>
#include <math.h>

#define BATCH 256
#define D 512
#define WPROW ((size_t)(D * D)) // 262144 floats per Wp row
#define AT_STRIDE 72            // A-tile row stride in ushorts (144 B: 64 bf16 + pad)

typedef __bf16  bf16x8  __attribute__((ext_vector_type(8)));
typedef __bf16  bf16x4  __attribute__((ext_vector_type(4)));
typedef float   floatx4 __attribute__((ext_vector_type(4)));

// ---------------- Kernel 1: mapping Linear + L2 normalize ----------------
__global__ __launch_bounds__(256)
void map_norm_kernel(const float* __restrict__ img_emb,
                     const float* __restrict__ txt_emb,
                     const float* __restrict__ Wi, const float* __restrict__ bi,
                     const float* __restrict__ Wt, const float* __restrict__ bt,
                     float* __restrict__ imgT,
                     float* __restrict__ txtN)
{
    const int b = blockIdx.x;
    const int is_txt = blockIdx.y;
    const int t = threadIdx.x;
    const float* emb = is_txt ? txt_emb : img_emb;
    const float* W   = is_txt ? Wt : Wi;
    const float* bv  = is_txt ? bt : bi;

    __shared__ float row[D];
    row[t]       = emb[(size_t)b * D + t];
    row[t + 256] = emb[(size_t)b * D + t + 256];
    __syncthreads();

    const int k0 = t, k1 = t + 256;
    float acc0 = bv[k0], acc1 = bv[k1];
    const float4* w0 = (const float4*)(W + (size_t)k0 * D);
    const float4* w1 = (const float4*)(W + (size_t)k1 * D);
    const float4* r4 = (const float4*)row;
#pragma unroll 8
    for (int p = 0; p < D / 4; ++p) {
        float4 rv = r4[p];
        float4 a  = w0[p];
        float4 c  = w1[p];
        acc0 += a.x * rv.x + a.y * rv.y + a.z * rv.z + a.w * rv.w;
        acc1 += c.x * rv.x + c.y * rv.y + c.z * rv.z + c.w * rv.w;
    }

    float ss = acc0 * acc0 + acc1 * acc1;
#pragma unroll
    for (int o = 32; o > 0; o >>= 1) ss += __shfl_down(ss, o);
    __shared__ float red[4];
    if ((t & 63) == 0) red[t >> 6] = ss;
    __syncthreads();
    float total = red[0] + red[1] + red[2] + red[3];
    float inv = 1.0f / fmaxf(sqrtf(total), 1e-12f);
    float v0 = acc0 * inv, v1 = acc1 * inv;

    if (is_txt) {
        txtN[(size_t)b * D + k0] = v0;
        txtN[(size_t)b * D + k1] = v1;
    } else {
        imgT[(size_t)k0 * BATCH + b] = v0;
        imgT[(size_t)k1 * BATCH + b] = v1;
    }
}

// ---------------- Kernel 2: barrier-free streaming bilinear GEMM ----------
// feats[b,k] = sum_{i,j} img[b,i] * txt[b,j] * Wp[k, i*512+j]
// Factored: partial[b,k] = sum_j bf16(txt[b,j]) * bf16(Wp[k,i*512+j]) (MFMA),
//           acc[b,k]    += img[b,i] (fp32) * partial[b,k]           (VALU).
// 512 WGs x 256 thr (2/CU): nt = wg&7 -> 64 Wp rows, ks = wg>>3 -> 8 i's.
// Wave = (mhalf = w&1: 128 batch rows, nslot = w>>1: 32 Wp rows).
// txt (bf16) lives in LDS per 64-col jb window (8 restages = only barriers).
// Wp streamed straight to VGPRs, register double-buffered -> only vmcnt
// traffic, fine-grained waits, no barrier drain in the steady-state loop.
__global__ __launch_bounds__(256, 2)
void bilinear_kernel(const float* __restrict__ txtN,  // [BATCH][D]
                     const float* __restrict__ imgT,  // [D][BATCH]
                     const float* __restrict__ Wp,    // [D][D*D]
                     float* __restrict__ feats)       // [BATCH][D], pre-zeroed
{
    __shared__ unsigned short Atile[256 * AT_STRIDE]; // 36,864 B
    __shared__ float imgL[8 * 256];                   // 8 KB

    const int wg    = blockIdx.x;
    const int nt    = wg & 7;   // 8 n-tiles of 64 cols
    const int ks    = wg >> 3;  // 64 K-splits of 8 i's
    const int tid   = threadIdx.x;
    const int lane  = tid & 63;
    const int wave  = tid >> 6;
    const int l15   = lane & 15;
    const int quad  = lane >> 4;
    const int mhalf = wave & 1;   // 128 batch rows
    const int nslot = wave >> 1;  // 32 Wp rows
    const int i0    = ks * 8;
    const int mbase = mhalf * 128;
    const int nrow0 = nt * 64 + nslot * 32 + l15;     // + n*16

    // Stage imgL[i][b] = img[b, i0+i] (8 x 256 floats), coalesced.
    {
        const int ii = tid >> 5;          // 0..7
        const int bb = (tid & 31) * 8;    // 0..248
        *(float4*)&imgL[ii * 256 + bb] =
            *(const float4*)&imgT[(size_t)(i0 + ii) * BATCH + bb];
        *(float4*)&imgL[ii * 256 + bb + 4] =
            *(const float4*)&imgT[(size_t)(i0 + ii) * BATCH + bb + 4];
    }

    floatx4 acc[8][2];
#pragma unroll
    for (int m = 0; m < 8; ++m)
#pragma unroll
        for (int n = 0; n < 2; ++n) acc[m][n] = (floatx4){0.f, 0.f, 0.f, 0.f};

    // Register-double-buffered Wp prefetch: 8 float4 per chunk per lane.
    float4 bp[2][8];
    auto prefetch = [&](int cc, float4* dst) {
        const int jb2 = cc >> 3, i2 = cc & 7;
        const size_t colb = (size_t)(i0 + i2) * D + jb2 * 64 + quad * 8;
#pragma unroll
        for (int n = 0; n < 2; ++n) {
            const float* base = Wp + (size_t)(nrow0 + n * 16) * WPROW + colb;
#pragma unroll
            for (int k = 0; k < 2; ++k) {
                dst[n * 4 + k * 2 + 0] = *(const float4*)(base + k * 32);
                dst[n * 4 + k * 2 + 1] = *(const float4*)(base + k * 32 + 4);
            }
        }
    };
    prefetch(0, bp[0]);

    int c = 0;
    for (int jb = 0; jb < 8; ++jb) {
        __syncthreads();
        // Stage Atile[b][col] = bf16(txt[b, jb*64+col]), 256x64, padded rows.
#pragma unroll
        for (int p = 0; p < 16; ++p) {
            const int r  = (tid >> 4) + p * 16;       // 0..255
            const int c8 = (tid & 15) * 4;            // 0..60
            float4 v = *(const float4*)&txtN[(size_t)r * D + jb * 64 + c8];
            bf16x4 h;
            h[0] = (__bf16)v.x; h[1] = (__bf16)v.y;
            h[2] = (__bf16)v.z; h[3] = (__bf16)v.w;
            *(bf16x4*)&Atile[r * AT_STRIDE + c8] = h;
        }
        __syncthreads();

#pragma unroll
        for (int i = 0; i < 8; ++i, ++c) {
            const float4* cur = bp[i & 1];
            const int cn = (c + 1 < 64) ? c + 1 : 63;
            prefetch(cn, bp[(i + 1) & 1]);

            // Convert current B chunk to bf16 fragments.
            bf16x8 bbf[2][2];
#pragma unroll
            for (int n = 0; n < 2; ++n)
#pragma unroll
                for (int k = 0; k < 2; ++k) {
                    const float4 x = cur[n * 4 + k * 2 + 0];
                    const float4 y = cur[n * 4 + k * 2 + 1];
                    bf16x8 v;
                    v[0] = (__bf16)x.x; v[1] = (__bf16)x.y;
                    v[2] = (__bf16)x.z; v[3] = (__bf16)x.w;
                    v[4] = (__bf16)y.x; v[5] = (__bf16)y.y;
                    v[6] = (__bf16)y.z; v[7] = (__bf16)y.w;
                    bbf[n][k] = v;
                }

#pragma unroll
            for (int m = 0; m < 8; ++m) {
                const int arow = mbase + m * 16 + l15;
                bf16x8 a0 = *(const bf16x8*)&Atile[arow * AT_STRIDE + quad * 8];
                bf16x8 a1 = *(const bf16x8*)&Atile[arow * AT_STRIDE + 32 + quad * 8];
                const float4 s =
                    *(const float4*)&imgL[i * 256 + mbase + m * 16 + quad * 4];
#pragma unroll
                for (int n = 0; n < 2; ++n) {
                    floatx4 p = __builtin_amdgcn_mfma_f32_16x16x32_bf16(
                        a0, bbf[n][0], (floatx4){0.f, 0.f, 0.f, 0.f}, 0, 0, 0);
                    p = __builtin_amdgcn_mfma_f32_16x16x32_bf16(
                        a1, bbf[n][1], p, 0, 0, 0);
                    acc[m][n][0] += s.x * p[0];
                    acc[m][n][1] += s.y * p[1];
                    acc[m][n][2] += s.z * p[2];
                    acc[m][n][3] += s.w * p[3];
                }
            }
        }
    }

    // Split-K reduction. C/D layout: col = lane&15, row = quad*4 + reg.
#pragma unroll
    for (int m = 0; m < 8; ++m)
#pragma unroll
        for (int n = 0; n < 2; ++n)
#pragma unroll
            for (int r = 0; r < 4; ++r) {
                const int brow = mbase + m * 16 + quad * 4 + r;
                const int kcol = nrow0 + n * 16;
                atomicAdd(&feats[(size_t)brow * D + kcol], acc[m][n][r]);
            }
}

// ---------------- Kernel 3: bias + ReLU + classifier + sigmoid ------------
__global__ __launch_bounds__(256)
void epilogue_kernel(const float* __restrict__ feats,
                     const float* __restrict__ bp,
                     const float* __restrict__ Wc,
                     const float* __restrict__ bc,
                     float* __restrict__ out)
{
    const int b = blockIdx.x;
    const int t = threadIdx.x;
    float v0 = fmaxf(feats[(size_t)b * D + t] + bp[t], 0.f) * Wc[t];
    float v1 = fmaxf(feats[(size_t)b * D + t + 256] + bp[t + 256], 0.f) * Wc[t + 256];
    float s = v0 + v1;
#pragma unroll
    for (int o = 32; o > 0; o >>= 1) s += __shfl_down(s, o);
    __shared__ float red[4];
    if ((t & 63) == 0) red[t >> 6] = s;
    __syncthreads();
    if (t == 0) {
        float tot = red[0] + red[1] + red[2] + red[3] + bc[0];
        out[b] = 1.0f / (1.0f + expf(-tot));
    }
}

extern "C" void kernel_launch(void* const* d_in, const int* in_sizes, int n_in,
                              void* d_out, int out_size, void* d_ws, size_t ws_size,
                              hipStream_t stream) {
    const float* image_embeds = (const float*)d_in[0];
    const float* text_embeds  = (const float*)d_in[1];
    const float* Wi = (const float*)d_in[2];
    const float* bi = (const float*)d_in[3];
    const float* Wt = (const float*)d_in[4];
    const float* bt = (const float*)d_in[5];
    const float* Wp = (const float*)d_in[6];
    const float* bp = (const float*)d_in[7];
    const float* Wc = (const float*)d_in[8];
    const float* bc = (const float*)d_in[9];
    float* out = (float*)d_out;

    float* txtN  = (float*)d_ws;            // 256*512 f32
    float* imgT  = txtN + BATCH * D;        // 512*256 f32
    float* feats = imgT + D * BATCH;        // 256*512 f32

    hipMemsetAsync(feats, 0, (size_t)BATCH * D * sizeof(float), stream);
    map_norm_kernel<<<dim3(BATCH, 2), 256, 0, stream>>>(
        image_embeds, text_embeds, Wi, bi, Wt, bt, imgT, txtN);
    bilinear_kernel<<<dim3(512), 256, 0, stream>>>(txtN, imgT, Wp, feats);
    epilogue_kernel<<<dim3(BATCH), 256, 0, stream>>>(feats, bp, Wc, bc, out);
}